// Round 4
// baseline (445.334 us; speedup 1.0000x reference)
//
#include <hip/hip_runtime.h>
#include <hip/hip_bf16.h>

// B=16, C=512, H=W=64, HW=4096, NH=8, HD=64, QK_CH=64.  FP32 I/O.
// Pipeline:
//  k_wcvt : Wq|Wk|Wv -> Wcat_b16[640][512], Wo -> Wo_b16[512][512]   (ws)
//  k_proj : qkv[b][o][s] = Wcat @ x[b] + bias  (MFMA), panel form:
//           block = 64 s-columns x ALL 640 outputs.  Phase 1 transposes the
//           full 512c x 64s x-panel into LDS bf16 ONCE (32x33 fp32 scratch
//           subtile transpose, conflict-free); phase 2 runs 16 K-steps with
//           a double-buffered full-m A-tile (640x32, global_load_lds with
//           WAVE-UNIFORM LDS base, stage-ahead + vmcnt(0)+barrier so DMA
//           hides under 40 MFMA/wave).  x is read exactly once per panel;
//           Wcat (640 KiB) is L2-resident.
//  k_attn : fused scores+softmax+apply per (b,head) (see below).
//  k_out  : d_out fp32 [65536][512] = Xb16 @ Wo_b16^T + bo  (MFMA)
// ws peak: 64 MiB (Xb16) + 1.2 MiB (weights).
// d_out used as qkv scratch [0,80 MiB) until k_out fully overwrites it.

#define B_  16
#define C_  512
#define HW_ 4096
#define NO_ 640

typedef unsigned short u16;
typedef __attribute__((ext_vector_type(8))) short bh8;   // 8 bf16 (4 VGPRs)
typedef __attribute__((ext_vector_type(4))) float f32x4; // MFMA C/D

__device__ __forceinline__ float bf2f(u16 u) {
    unsigned v = ((unsigned)u) << 16;
    return __uint_as_float(v);
}
__device__ __forceinline__ u16 f2bf(float f) {
    unsigned u = __float_as_uint(f);
    unsigned r = (u + 0x7FFFu + ((u >> 16) & 1u)) >> 16;  // RNE
    return (u16)r;
}

// async global->LDS, 16 B per lane; LDS dest = wave-uniform base + lane*16.
__device__ __forceinline__ void gl2lds(const u16* g, u16* l) {
    __builtin_amdgcn_global_load_lds(
        (const __attribute__((address_space(1))) unsigned int*)(const void*)g,
        (__attribute__((address_space(3))) unsigned int*)(void*)l, 16, 0, 0);
}

// ---------------- weight conversion ----------------
__global__ __launch_bounds__(256) void k_wcvt(
    const float* __restrict__ Wq, const float* __restrict__ Wk,
    const float* __restrict__ Wv, const float* __restrict__ Wo,
    u16* __restrict__ Wcat, u16* __restrict__ Wob)
{
    int idx = blockIdx.x * 256 + threadIdx.x;
    if (idx < NO_ * C_) {
        int o = idx >> 9, c = idx & 511;
        float v = (o < 64) ? Wq[o * C_ + c]
                : (o < 128) ? Wk[(o - 64) * C_ + c]
                : Wv[(size_t)(o - 128) * C_ + c];
        Wcat[idx] = f2bf(v);
    }
    int idx2 = idx - NO_ * C_;
    if (idx2 >= 0 && idx2 < C_ * C_) Wob[idx2] = f2bf(Wo[idx2]);
}

// ---------------- k_proj (MFMA, panel): qkv[b][o][s] = Wcat @ x[b] + bias ----
// grid (64 n-panels, 1, 16 b), 256 threads (4 waves).  LDS 145 KiB:
//   As[2][640*32] u16 (81920 B, double-buffered A K-slices; phase-1 scratch
//   aliases buffer 0) + Bs[64*520] u16 (66560 B, resident bf16 x^T panel,
//   pitch 520 -> b128 fragment reads at bank floor).
// Wave w computes m-rows [w*160, w*160+160) x all 64 s.
__global__ __launch_bounds__(256, 1) void k_proj(
    const u16* __restrict__ Wcat, const float* __restrict__ x,
    const float* __restrict__ bq, const float* __restrict__ bk,
    const float* __restrict__ bv, u16* __restrict__ qkv)
{
    __shared__ u16 As[2][NO_ * 32];     // 2 x 40960 B
    __shared__ u16 Bs[64 * 520];        // 66560 B
    const int t = threadIdx.x;
    const int lane = t & 63, w = t >> 6;
    const int q = lane >> 4, ln = lane & 15;
    const int n0 = blockIdx.x * 64, b = blockIdx.z;
    const float* xb = x + (size_t)b * C_ * HW_ + n0;

    // ---- phase 1: x[c][n0+s] (512c x 64s) -> Bs[s][c] bf16, via 32x32
    //      subtiles double-transposed through a per-wave [32][33] fp32 tile.
    {
        float* T = (float*)&As[0][0] + w * 1088;   // 4352 B per wave
        const int la = lane & 7, lb = lane >> 3;
        for (int g = 0; g < 4; ++g) {
            const int c0 = (w + 4 * g) * 32;
            for (int st = 0; st < 2; ++st) {
                const int s0 = st * 32;
#pragma unroll
                for (int it = 0; it < 4; ++it) {
                    int c = lb + it * 8;
                    float4 v = *(const float4*)(xb + (size_t)(c0 + c) * HW_ + s0 + la * 4);
                    T[c * 33 + la * 4 + 0] = v.x;
                    T[c * 33 + la * 4 + 1] = v.y;
                    T[c * 33 + la * 4 + 2] = v.z;
                    T[c * 33 + la * 4 + 3] = v.w;
                }
                __syncthreads();
#pragma unroll
                for (int it = 0; it < 4; ++it) {
                    int s = lb + it * 8;
                    ushort4 o;
                    o.x = f2bf(T[(la * 4 + 0) * 33 + s]);
                    o.y = f2bf(T[(la * 4 + 1) * 33 + s]);
                    o.z = f2bf(T[(la * 4 + 2) * 33 + s]);
                    o.w = f2bf(T[(la * 4 + 3) * 33 + s]);
                    *(ushort4*)&Bs[(s0 + s) * 520 + c0 + la * 4] = o;
                }
                __syncthreads();
            }
        }
    }
    __syncthreads();

    // ---- phase 2: 16 K-steps, double-buffered full-m A-tile ----
    const int mw = w * 160;
    f32x4 acc[10][4];
#pragma unroll
    for (int i = 0; i < 10; ++i)
#pragma unroll
        for (int j = 0; j < 4; ++j) acc[i][j] = (f32x4){0.f, 0.f, 0.f, 0.f};

    // staging: per wave-block of 16 rows, LDS base is WAVE-UNIFORM; all
    // lane-dependence lives in the global address (proven gl2lds idiom).
    const int srow = lane >> 2, scol = (lane & 3) * 8;
#define STAGE_A(BUF, K0)                                                     \
    _Pragma("unroll")                                                        \
    for (int i_ = 0; i_ < 10; ++i_) {                                        \
        int rowblk_ = (i_ * 4 + w) * 16;                                     \
        gl2lds(Wcat + (size_t)(rowblk_ + srow) * C_ + (K0) + scol,           \
               &As[BUF][rowblk_ * 32]);                                      \
    }

    STAGE_A(0, 0)
    asm volatile("s_waitcnt vmcnt(0)" ::: "memory");
    __syncthreads();

    for (int kt = 0; kt < 16; ++kt) {
        const int cur = kt & 1;
        if (kt < 15) { STAGE_A(cur ^ 1, (kt + 1) * 32) }
        bh8 bf[4];
#pragma unroll
        for (int j = 0; j < 4; ++j)
            bf[j] = *(const bh8*)&Bs[(j * 16 + ln) * 520 + kt * 32 + q * 8];
#pragma unroll
        for (int i = 0; i < 10; ++i) {
            bh8 af = *(const bh8*)&As[cur][(mw + i * 16 + ln) * 32 + q * 8];
#pragma unroll
            for (int j = 0; j < 4; ++j)
                acc[i][j] = __builtin_amdgcn_mfma_f32_16x16x32_bf16(af, bf[j], acc[i][j], 0, 0, 0);
        }
        asm volatile("s_waitcnt vmcnt(0)" ::: "memory");
        __syncthreads();
    }
#undef STAGE_A

    // ---- epilogue: bias + store bf16 ----
    u16* qb = qkv + (size_t)b * NO_ * HW_;
#pragma unroll
    for (int i = 0; i < 10; ++i) {
#pragma unroll
        for (int r = 0; r < 4; ++r) {
            int o = mw + i * 16 + q * 4 + r;
            float bia = (o < 64) ? bq[o] : (o < 128) ? bk[o - 64] : bv[o - 128];
#pragma unroll
            for (int j = 0; j < 4; ++j) {
                int s = n0 + j * 16 + ln;
                qb[(size_t)o * HW_ + s] = f2bf(acc[i][j][r] + bia);
            }
        }
    }
}

// ---------------- k_attn: fused scores + softmax + apply ----------------
// grid (4 hs, 8 head, 16 b), 512 threads (8 waves).
// Scores: S[d][e] = sum_l Q[d][l] K[e][l], l<512; element (d,l) of Q lives at
// qbase + (l>>6)*HW + (l&63)*64 + d.  Staged per 64-l macro-step as an LDS
// transpose (pitch 72).  Waves w&3 = m-tile; w>>2 duplicates (redundant).
// Softmax rows in registers (shfl_xor over 16-lane groups), P -> LDS bf16.
// Apply: D[a][w'] = sum_e V[a][h*64+e] * P[w'][e]; V fragments straight from
// global with 1-deep register prefetch, P fragments hoisted from LDS once.
__global__ __launch_bounds__(512) void k_attn(
    const u16* __restrict__ qkv, u16* __restrict__ Xb16)
{
    __shared__ u16 Qs[64 * 72];
    __shared__ u16 Ks[64 * 72];
    __shared__ u16 Ps[64 * 72];
    const int t = threadIdx.x;
    const int lane = t & 63, w = t >> 6;
    const int q = lane >> 4, ln = lane & 15;
    const int hbase = blockIdx.x * 16, head = blockIdx.y, b = blockIdx.z;
    const u16* qbase = qkv + ((size_t)b * NO_ + 8 * head) * HW_;
    const u16* kbase = qkv + ((size_t)b * NO_ + 64 + 8 * head) * HW_;
    const u16* Vg    = qkv + ((size_t)b * NO_ + 128 + 64 * head) * HW_;
    u16* ob = Xb16 + ((size_t)b * C_ + head) * HW_;

    const int m0 = (w & 3) * 16;       // scores m-tile / apply a-tile
    const int sl = t & 63;             // staging: l_lo
    const int sg = t >> 6;             // staging: d-group (8 d's per thread)

    // ---- scores: S = Q K^T over K=512, 8 macro-steps of 64 ----
    f32x4 acc[4];
#pragma unroll
    for (int j = 0; j < 4; ++j) acc[j] = (f32x4){0.f, 0.f, 0.f, 0.f};

    for (int c0 = 0; c0 < 8; ++c0) {
        __syncthreads();
        bh8 qv = *(const bh8*)(qbase + (size_t)c0 * HW_ + sl * 64 + sg * 8);
        bh8 kv = *(const bh8*)(kbase + (size_t)c0 * HW_ + sl * 64 + sg * 8);
#pragma unroll
        for (int i = 0; i < 8; ++i) {
            Qs[(sg * 8 + i) * 72 + sl] = (u16)qv[i];
            Ks[(sg * 8 + i) * 72 + sl] = (u16)kv[i];
        }
        __syncthreads();
        bh8 aq[2], bk_[4][2];
#pragma unroll
        for (int ks = 0; ks < 2; ++ks)
            aq[ks] = *(const bh8*)&Qs[(m0 + ln) * 72 + ks * 32 + q * 8];
#pragma unroll
        for (int j = 0; j < 4; ++j)
#pragma unroll
            for (int ks = 0; ks < 2; ++ks)
                bk_[j][ks] = *(const bh8*)&Ks[(j * 16 + ln) * 72 + ks * 32 + q * 8];
#pragma unroll
        for (int ks = 0; ks < 2; ++ks)
#pragma unroll
            for (int j = 0; j < 4; ++j)
                acc[j] = __builtin_amdgcn_mfma_f32_16x16x32_bf16(aq[ks], bk_[j][ks], acc[j], 0, 0, 0);
    }

    // ---- softmax over e (scale 1/sqrt(64) = 0.125), P -> LDS bf16 ----
#pragma unroll
    for (int r = 0; r < 4; ++r) {
        float pv[4];
        float mx = -1e30f;
#pragma unroll
        for (int j = 0; j < 4; ++j) {
            pv[j] = acc[j][r] * 0.125f;
            mx = fmaxf(mx, pv[j]);
        }
#pragma unroll
        for (int m = 1; m < 16; m <<= 1) mx = fmaxf(mx, __shfl_xor(mx, m));
        float ssum = 0.f;
#pragma unroll
        for (int j = 0; j < 4; ++j) { pv[j] = __expf(pv[j] - mx); ssum += pv[j]; }
#pragma unroll
        for (int m = 1; m < 16; m <<= 1) ssum += __shfl_xor(ssum, m);
        float inv = 1.f / ssum;
        if (w < 4) {
#pragma unroll
            for (int j = 0; j < 4; ++j)
                Ps[(m0 + q * 4 + r) * 72 + j * 16 + ln] = f2bf(pv[j] * inv);
        }
    }
    __syncthreads();

    // ---- apply: D[a][w'] = sum_e V[a][h*64+e] P[w'][e], 8 h per wave ----
    const int a0 = m0;
    const int h0 = hbase + (w >> 2) * 8;
    bh8 pb[4][2];
#pragma unroll
    for (int j = 0; j < 4; ++j)
#pragma unroll
        for (int ks = 0; ks < 2; ++ks)
            pb[j][ks] = *(const bh8*)&Ps[(j * 16 + ln) * 72 + ks * 32 + q * 8];

    const u16* vrow = Vg + (size_t)(a0 + ln) * HW_;
    bh8 vf0[2], vf1[2];
#pragma unroll
    for (int ks = 0; ks < 2; ++ks)
        vf0[ks] = *(const bh8*)(vrow + h0 * 64 + ks * 32 + q * 8);
#pragma unroll
    for (int hi = 0; hi < 8; ++hi) {
        const int h = h0 + hi;
        if (hi < 7) {
#pragma unroll
            for (int ks = 0; ks < 2; ++ks)
                vf1[ks] = *(const bh8*)(vrow + (h + 1) * 64 + ks * 32 + q * 8);
        }
        f32x4 a2[4];
#pragma unroll
        for (int j = 0; j < 4; ++j) a2[j] = (f32x4){0.f, 0.f, 0.f, 0.f};
#pragma unroll
        for (int ks = 0; ks < 2; ++ks)
#pragma unroll
            for (int j = 0; j < 4; ++j)
                a2[j] = __builtin_amdgcn_mfma_f32_16x16x32_bf16(vf0[ks], pb[j][ks], a2[j], 0, 0, 0);

        // X layout: channel c = a*8 + head, spatial h*64+w'.
#pragma unroll
        for (int r = 0; r < 4; ++r) {
            int a = a0 + q * 4 + r;
            u16* orow = ob + (size_t)a * 8 * HW_ + h * 64;
#pragma unroll
            for (int j = 0; j < 4; ++j) orow[j * 16 + ln] = f2bf(a2[j][r]);
        }
#pragma unroll
        for (int ks = 0; ks < 2; ++ks) vf0[ks] = vf1[ks];
    }
}

// ---------------- k_out (MFMA): Y = Xb16 @ Wo_b16^T + bo, fp32 out ----------------
// A = Xb16[65536][512] ([m][k]), B = Wo_b16[512][512] ([n][k]). Tile 128x128, BK=32.
__global__ __launch_bounds__(256) void k_out(
    const u16* __restrict__ Xg, const u16* __restrict__ Wob,
    const float* __restrict__ bo, float* __restrict__ Y)
{
    __shared__ u16 As[128 * 32];
    __shared__ u16 Bs[128 * 32];
    const int t = threadIdx.x;
    const int lane = t & 63, w = t >> 6;
    const int q = lane >> 4, ln = lane & 15;
    const int n0 = blockIdx.x * 128;
    const size_t r0 = (size_t)blockIdx.y * 128;
    const int wm = (w >> 1) * 64, wn = (w & 1) * 64;
    const int srow = lane >> 2, scol = (lane & 3) * 8;

    f32x4 acc[4][4];
#pragma unroll
    for (int i = 0; i < 4; ++i)
#pragma unroll
        for (int j = 0; j < 4; ++j) acc[i][j] = (f32x4){0.f, 0.f, 0.f, 0.f};

    for (int k0 = 0; k0 < C_; k0 += 32) {
        __syncthreads();
#pragma unroll
        for (int i = 0; i < 2; ++i) {
            int rowblk = (i * 4 + w) * 16;
            gl2lds(Xg  + (r0 + rowblk + srow) * C_ + k0 + scol, &As[rowblk * 32]);
            gl2lds(Wob + (size_t)(n0 + rowblk + srow) * C_ + k0 + scol, &Bs[rowblk * 32]);
        }
        __syncthreads();
        bh8 af[4], bfv[4];
#pragma unroll
        for (int i = 0; i < 4; ++i) af[i]  = *(const bh8*)&As[(wm + i * 16 + ln) * 32 + q * 8];
#pragma unroll
        for (int j = 0; j < 4; ++j) bfv[j] = *(const bh8*)&Bs[(wn + j * 16 + ln) * 32 + q * 8];
#pragma unroll
        for (int i = 0; i < 4; ++i)
#pragma unroll
            for (int j = 0; j < 4; ++j)
                acc[i][j] = __builtin_amdgcn_mfma_f32_16x16x32_bf16(af[i], bfv[j], acc[i][j], 0, 0, 0);
    }

#pragma unroll
    for (int i = 0; i < 4; ++i) {
#pragma unroll
        for (int r = 0; r < 4; ++r) {
            size_t row = r0 + wm + i * 16 + q * 4 + r;
#pragma unroll
            for (int j = 0; j < 4; ++j) {
                int col = n0 + wn + j * 16 + ln;
                Y[row * C_ + col] = acc[i][j][r] + bo[col];
            }
        }
    }
}

extern "C" void kernel_launch(void* const* d_in, const int* in_sizes, int n_in,
                              void* d_out, int out_size, void* d_ws, size_t ws_size,
                              hipStream_t stream)
{
    const float* x  = (const float*)d_in[0];
    const float* Wq = (const float*)d_in[1];
    const float* bq = (const float*)d_in[2];
    const float* Wk = (const float*)d_in[3];
    const float* bk = (const float*)d_in[4];
    const float* Wv = (const float*)d_in[5];
    const float* bv = (const float*)d_in[6];
    const float* Wo = (const float*)d_in[7];
    const float* bo = (const float*)d_in[8];

    char* ws = (char*)d_ws;
    u16*   Xb16 = (u16*)ws;                              // [0, 64 MiB)
    u16*   Wcat = (u16*)(ws + 67108864 + 2097152);       // 655,360 B
    u16*   Wob  = (u16*)(ws + 67108864 + 2097152 + 655360); // 524,288 B
    u16*   qkv  = (u16*)d_out;                           // 80 MiB scratch in d_out
    float* Y    = (float*)d_out;

    k_wcvt <<<dim3((NO_ * C_ + C_ * C_ + 255) / 256), 256, 0, stream>>>(Wq, Wk, Wv, Wo, Wcat, Wob);
    k_proj <<<dim3(HW_ / 64, 1, B_), 256, 0, stream>>>(Wcat, x, bq, bk, bv, qkv);
    k_attn <<<dim3(4, 8, B_), 512, 0, stream>>>(qkv, Xb16);
    k_out  <<<dim3(C_ / 128, (B_ * HW_) / 128), 256, 0, stream>>>(Xb16, Wob, bo, Y);
}

// Round 5
// 388.838 us; speedup vs baseline: 1.1453x; 1.1453x over previous
//
#include <hip/hip_runtime.h>
#include <hip/hip_bf16.h>

// B=16, C=512, H=W=64, HW=4096, NH=8, HD=64, QK_CH=64.  FP32 I/O.
// Pipeline:
//  k_wcvt : Wq|Wk|Wv -> Wcat_b16[640][512], Wo -> Wo_b16[512][512]   (ws)
//  k_proj : qkv[b][o][s] = Wcat @ x[b] + bias  (MFMA, 128x128 tile, BK=32).
//           B-operand transposed ON THE FLY from fp32 x[b][c][s]:
//           per K-step each thread loads a 4s x 4c sub-tile as 4x float4
//           (coalesced), converts via v_cvt_pk_bf16_f32 (8 VALU), and
//           ds_writes transposed into a padded LDS layout
//           addr(s,c) = s*32 + (s>>2)*8 + c  (+16B pad per 4 rows) ->
//           writes hit all 32 banks evenly (zero conflict), reads stay
//           16B-aligned b128 at the wave floor.  Next-step loads issued
//           before the MFMAs (latency hidden).  A-side via global_load_lds.
//  k_attn : fused scores+softmax+apply per (b,head) (see below).
//  k_out  : d_out fp32 [65536][512] = Xb16 @ Wo_b16^T + bo  (MFMA)
// ws peak: 64 MiB (Xb16) + 1.2 MiB (weights).
// d_out used as qkv scratch [0,80 MiB) until k_out fully overwrites it.

#define B_  16
#define C_  512
#define HW_ 4096
#define NO_ 640

typedef unsigned short u16;
typedef unsigned int   u32;
typedef __attribute__((ext_vector_type(8))) short bh8;   // 8 bf16 (4 VGPRs)
typedef __attribute__((ext_vector_type(4))) float f32x4; // MFMA C/D

__device__ __forceinline__ float bf2f(u16 u) {
    unsigned v = ((unsigned)u) << 16;
    return __uint_as_float(v);
}
__device__ __forceinline__ u16 f2bf(float f) {
    unsigned u = __float_as_uint(f);
    unsigned r = (u + 0x7FFFu + ((u >> 16) & 1u)) >> 16;  // RNE
    return (u16)r;
}
// pack 2 f32 -> 2 bf16 (RNE), lo in low 16 bits (T12 recipe, m240).
__device__ __forceinline__ u32 cvtpk(float lo, float hi) {
    u32 r;
    asm("v_cvt_pk_bf16_f32 %0, %1, %2" : "=v"(r) : "v"(lo), "v"(hi));
    return r;
}

// async global->LDS, 16 B per lane; LDS dest = wave-uniform base + lane*16.
__device__ __forceinline__ void gl2lds(const u16* g, u16* l) {
    __builtin_amdgcn_global_load_lds(
        (const __attribute__((address_space(1))) unsigned int*)(const void*)g,
        (__attribute__((address_space(3))) unsigned int*)(void*)l, 16, 0, 0);
}

// ---------------- weight conversion ----------------
__global__ __launch_bounds__(256) void k_wcvt(
    const float* __restrict__ Wq, const float* __restrict__ Wk,
    const float* __restrict__ Wv, const float* __restrict__ Wo,
    u16* __restrict__ Wcat, u16* __restrict__ Wob)
{
    int idx = blockIdx.x * 256 + threadIdx.x;
    if (idx < NO_ * C_) {
        int o = idx >> 9, c = idx & 511;
        float v = (o < 64) ? Wq[o * C_ + c]
                : (o < 128) ? Wk[(o - 64) * C_ + c]
                : Wv[(size_t)(o - 128) * C_ + c];
        Wcat[idx] = f2bf(v);
    }
    int idx2 = idx - NO_ * C_;
    if (idx2 >= 0 && idx2 < C_ * C_) Wob[idx2] = f2bf(Wo[idx2]);
}

// ---------------- k_proj (MFMA): qkv[b][o][s] = Wcat @ x[b] + bias ----------------
// A = Wcat[640][512] ([m][k], bf16, gl2lds).  B from x[b][c][s] fp32, transposed
// into padded LDS per K-step.  Tile 128x128, BK=32.  grid (32 n, 5 m, 16 b).
#define LDSB(s, c) ((((s) << 5) + (((s) >> 2) << 3)) + (c))   // u16 index
__global__ __launch_bounds__(256) void k_proj(
    const u16* __restrict__ Wcat, const float* __restrict__ x,
    const float* __restrict__ bq, const float* __restrict__ bk,
    const float* __restrict__ bv, u16* __restrict__ qkv)
{
    __shared__ u16 As[128 * 32];
    __shared__ u16 Bs[128 * 32 + 32 * 8];   // +16B pad per 4 rows
    const int t = threadIdx.x;
    const int lane = t & 63, w = t >> 6;
    const int q = lane >> 4, ln = lane & 15;
    const int n0 = blockIdx.x * 128, m0 = blockIdx.y * 128, b = blockIdx.z;
    const float* xb = x + (size_t)b * C_ * HW_;
    const int wm = (w >> 1) * 64, wn = (w & 1) * 64;
    const int srow = lane >> 2, scol = (lane & 3) * 8;
    // B staging: thread owns s in [sb,sb+4), c in [cb,cb+4) of the 128x32 tile
    const int sb = (t & 31) * 4;
    const int cb = (t >> 5) * 4;
    const float* xs = xb + n0 + sb;

    f32x4 acc[4][4];
#pragma unroll
    for (int i = 0; i < 4; ++i)
#pragma unroll
        for (int j = 0; j < 4; ++j) acc[i][j] = (f32x4){0.f, 0.f, 0.f, 0.f};

    // prologue: first x sub-tile into registers (4x float4, coalesced)
    float4 xv[4];
#pragma unroll
    for (int i = 0; i < 4; ++i)
        xv[i] = *(const float4*)(xs + (size_t)(cb + i) * HW_);

    for (int k0 = 0; k0 < C_; k0 += 32) {
        __syncthreads();
        // stage A (async DMA) and B (transposed from regs, conflict-free)
#pragma unroll
        for (int i = 0; i < 2; ++i) {
            int rowblk = (i * 4 + w) * 16;
            gl2lds(Wcat + (size_t)(m0 + rowblk + srow) * C_ + k0 + scol, &As[rowblk * 32]);
        }
#pragma unroll
        for (int j = 0; j < 4; ++j) {
            uint2 o;
            o.x = cvtpk(((const float*)&xv[0])[j], ((const float*)&xv[1])[j]);
            o.y = cvtpk(((const float*)&xv[2])[j], ((const float*)&xv[3])[j]);
            *(uint2*)&Bs[LDSB(sb + j, cb)] = o;
        }
        __syncthreads();
        // issue next-step x loads (latency hides under MFMAs)
        if (k0 + 32 < C_) {
#pragma unroll
            for (int i = 0; i < 4; ++i)
                xv[i] = *(const float4*)(xs + (size_t)(k0 + 32 + cb + i) * HW_);
        }
        bh8 af[4], bfv[4];
#pragma unroll
        for (int i = 0; i < 4; ++i) af[i]  = *(const bh8*)&As[(wm + i * 16 + ln) * 32 + q * 8];
#pragma unroll
        for (int j = 0; j < 4; ++j) bfv[j] = *(const bh8*)&Bs[LDSB(wn + j * 16 + ln, q * 8)];
#pragma unroll
        for (int i = 0; i < 4; ++i)
#pragma unroll
            for (int j = 0; j < 4; ++j)
                acc[i][j] = __builtin_amdgcn_mfma_f32_16x16x32_bf16(af[i], bfv[j], acc[i][j], 0, 0, 0);
    }

    u16* qb = qkv + (size_t)b * NO_ * HW_;
#pragma unroll
    for (int i = 0; i < 4; ++i) {
#pragma unroll
        for (int r = 0; r < 4; ++r) {
            int o = m0 + wm + i * 16 + q * 4 + r;
            float bia = (o < 64) ? bq[o] : (o < 128) ? bk[o - 64] : bv[o - 128];
#pragma unroll
            for (int j = 0; j < 4; ++j) {
                int s = n0 + wn + j * 16 + ln;
                qb[(size_t)o * HW_ + s] = f2bf(acc[i][j][r] + bia);
            }
        }
    }
}

// ---------------- k_attn: fused scores + softmax + apply ----------------
// grid (4 hs, 8 head, 16 b), 512 threads (8 waves).
// Scores: S[d][e] = sum_l Q[d][l] K[e][l], l<512; element (d,l) of Q lives at
// qbase + (l>>6)*HW + (l&63)*64 + d.  Staged per 64-l macro-step as an LDS
// transpose (pitch 72).  Waves w&3 = m-tile; w>>2 duplicates (redundant).
// Softmax rows in registers (shfl_xor over 16-lane groups), P -> LDS bf16.
// Apply: D[a][w'] = sum_e V[a][h*64+e] * P[w'][e]; V fragments straight from
// global with 1-deep register prefetch, P fragments hoisted from LDS once.
__global__ __launch_bounds__(512) void k_attn(
    const u16* __restrict__ qkv, u16* __restrict__ Xb16)
{
    __shared__ u16 Qs[64 * 72];
    __shared__ u16 Ks[64 * 72];
    __shared__ u16 Ps[64 * 72];
    const int t = threadIdx.x;
    const int lane = t & 63, w = t >> 6;
    const int q = lane >> 4, ln = lane & 15;
    const int hbase = blockIdx.x * 16, head = blockIdx.y, b = blockIdx.z;
    const u16* qbase = qkv + ((size_t)b * NO_ + 8 * head) * HW_;
    const u16* kbase = qkv + ((size_t)b * NO_ + 64 + 8 * head) * HW_;
    const u16* Vg    = qkv + ((size_t)b * NO_ + 128 + 64 * head) * HW_;
    u16* ob = Xb16 + ((size_t)b * C_ + head) * HW_;

    const int m0 = (w & 3) * 16;       // scores m-tile / apply a-tile
    const int sl = t & 63;             // staging: l_lo
    const int sg = t >> 6;             // staging: d-group (8 d's per thread)

    // ---- scores: S = Q K^T over K=512, 8 macro-steps of 64 ----
    f32x4 acc[4];
#pragma unroll
    for (int j = 0; j < 4; ++j) acc[j] = (f32x4){0.f, 0.f, 0.f, 0.f};

    for (int c0 = 0; c0 < 8; ++c0) {
        __syncthreads();
        bh8 qv = *(const bh8*)(qbase + (size_t)c0 * HW_ + sl * 64 + sg * 8);
        bh8 kv = *(const bh8*)(kbase + (size_t)c0 * HW_ + sl * 64 + sg * 8);
#pragma unroll
        for (int i = 0; i < 8; ++i) {
            Qs[(sg * 8 + i) * 72 + sl] = (u16)qv[i];
            Ks[(sg * 8 + i) * 72 + sl] = (u16)kv[i];
        }
        __syncthreads();
        bh8 aq[2], bk_[4][2];
#pragma unroll
        for (int ks = 0; ks < 2; ++ks)
            aq[ks] = *(const bh8*)&Qs[(m0 + ln) * 72 + ks * 32 + q * 8];
#pragma unroll
        for (int j = 0; j < 4; ++j)
#pragma unroll
            for (int ks = 0; ks < 2; ++ks)
                bk_[j][ks] = *(const bh8*)&Ks[(j * 16 + ln) * 72 + ks * 32 + q * 8];
#pragma unroll
        for (int ks = 0; ks < 2; ++ks)
#pragma unroll
            for (int j = 0; j < 4; ++j)
                acc[j] = __builtin_amdgcn_mfma_f32_16x16x32_bf16(aq[ks], bk_[j][ks], acc[j], 0, 0, 0);
    }

    // ---- softmax over e (scale 1/sqrt(64) = 0.125), P -> LDS bf16 ----
#pragma unroll
    for (int r = 0; r < 4; ++r) {
        float pv[4];
        float mx = -1e30f;
#pragma unroll
        for (int j = 0; j < 4; ++j) {
            pv[j] = acc[j][r] * 0.125f;
            mx = fmaxf(mx, pv[j]);
        }
#pragma unroll
        for (int m = 1; m < 16; m <<= 1) mx = fmaxf(mx, __shfl_xor(mx, m));
        float ssum = 0.f;
#pragma unroll
        for (int j = 0; j < 4; ++j) { pv[j] = __expf(pv[j] - mx); ssum += pv[j]; }
#pragma unroll
        for (int m = 1; m < 16; m <<= 1) ssum += __shfl_xor(ssum, m);
        float inv = 1.f / ssum;
        if (w < 4) {
#pragma unroll
            for (int j = 0; j < 4; ++j)
                Ps[(m0 + q * 4 + r) * 72 + j * 16 + ln] = f2bf(pv[j] * inv);
        }
    }
    __syncthreads();

    // ---- apply: D[a][w'] = sum_e V[a][h*64+e] P[w'][e], 8 h per wave ----
    const int a0 = m0;
    const int h0 = hbase + (w >> 2) * 8;
    bh8 pb[4][2];
#pragma unroll
    for (int j = 0; j < 4; ++j)
#pragma unroll
        for (int ks = 0; ks < 2; ++ks)
            pb[j][ks] = *(const bh8*)&Ps[(j * 16 + ln) * 72 + ks * 32 + q * 8];

    const u16* vrow = Vg + (size_t)(a0 + ln) * HW_;
    bh8 vf0[2], vf1[2];
#pragma unroll
    for (int ks = 0; ks < 2; ++ks)
        vf0[ks] = *(const bh8*)(vrow + h0 * 64 + ks * 32 + q * 8);
#pragma unroll
    for (int hi = 0; hi < 8; ++hi) {
        const int h = h0 + hi;
        if (hi < 7) {
#pragma unroll
            for (int ks = 0; ks < 2; ++ks)
                vf1[ks] = *(const bh8*)(vrow + (h + 1) * 64 + ks * 32 + q * 8);
        }
        f32x4 a2[4];
#pragma unroll
        for (int j = 0; j < 4; ++j) a2[j] = (f32x4){0.f, 0.f, 0.f, 0.f};
#pragma unroll
        for (int ks = 0; ks < 2; ++ks)
#pragma unroll
            for (int j = 0; j < 4; ++j)
                a2[j] = __builtin_amdgcn_mfma_f32_16x16x32_bf16(vf0[ks], pb[j][ks], a2[j], 0, 0, 0);

        // X layout: channel c = a*8 + head, spatial h*64+w'.
#pragma unroll
        for (int r = 0; r < 4; ++r) {
            int a = a0 + q * 4 + r;
            u16* orow = ob + (size_t)a * 8 * HW_ + h * 64;
#pragma unroll
            for (int j = 0; j < 4; ++j) orow[j * 16 + ln] = f2bf(a2[j][r]);
        }
#pragma unroll
        for (int ks = 0; ks < 2; ++ks) vf0[ks] = vf1[ks];
    }
}

// ---------------- k_out (MFMA): Y = Xb16 @ Wo_b16^T + bo, fp32 out ----------------
// A = Xb16[65536][512] ([m][k]), B = Wo_b16[512][512] ([n][k]). Tile 128x128, BK=32.
__global__ __launch_bounds__(256) void k_out(
    const u16* __restrict__ Xg, const u16* __restrict__ Wob,
    const float* __restrict__ bo, float* __restrict__ Y)
{
    __shared__ u16 As[128 * 32];
    __shared__ u16 Bs[128 * 32];
    const int t = threadIdx.x;
    const int lane = t & 63, w = t >> 6;
    const int q = lane >> 4, ln = lane & 15;
    const int n0 = blockIdx.x * 128;
    const size_t r0 = (size_t)blockIdx.y * 128;
    const int wm = (w >> 1) * 64, wn = (w & 1) * 64;
    const int srow = lane >> 2, scol = (lane & 3) * 8;

    f32x4 acc[4][4];
#pragma unroll
    for (int i = 0; i < 4; ++i)
#pragma unroll
        for (int j = 0; j < 4; ++j) acc[i][j] = (f32x4){0.f, 0.f, 0.f, 0.f};

    for (int k0 = 0; k0 < C_; k0 += 32) {
        __syncthreads();
#pragma unroll
        for (int i = 0; i < 2; ++i) {
            int rowblk = (i * 4 + w) * 16;
            gl2lds(Xg  + (r0 + rowblk + srow) * C_ + k0 + scol, &As[rowblk * 32]);
            gl2lds(Wob + (size_t)(n0 + rowblk + srow) * C_ + k0 + scol, &Bs[rowblk * 32]);
        }
        __syncthreads();
        bh8 af[4], bfv[4];
#pragma unroll
        for (int i = 0; i < 4; ++i) af[i]  = *(const bh8*)&As[(wm + i * 16 + ln) * 32 + q * 8];
#pragma unroll
        for (int j = 0; j < 4; ++j) bfv[j] = *(const bh8*)&Bs[(wn + j * 16 + ln) * 32 + q * 8];
#pragma unroll
        for (int i = 0; i < 4; ++i)
#pragma unroll
            for (int j = 0; j < 4; ++j)
                acc[i][j] = __builtin_amdgcn_mfma_f32_16x16x32_bf16(af[i], bfv[j], acc[i][j], 0, 0, 0);
    }

#pragma unroll
    for (int i = 0; i < 4; ++i) {
#pragma unroll
        for (int r = 0; r < 4; ++r) {
            size_t row = r0 + wm + i * 16 + q * 4 + r;
#pragma unroll
            for (int j = 0; j < 4; ++j) {
                int col = n0 + wn + j * 16 + ln;
                Y[row * C_ + col] = acc[i][j][r] + bo[col];
            }
        }
    }
}

extern "C" void kernel_launch(void* const* d_in, const int* in_sizes, int n_in,
                              void* d_out, int out_size, void* d_ws, size_t ws_size,
                              hipStream_t stream)
{
    const float* x  = (const float*)d_in[0];
    const float* Wq = (const float*)d_in[1];
    const float* bq = (const float*)d_in[2];
    const float* Wk = (const float*)d_in[3];
    const float* bk = (const float*)d_in[4];
    const float* Wv = (const float*)d_in[5];
    const float* bv = (const float*)d_in[6];
    const float* Wo = (const float*)d_in[7];
    const float* bo = (const float*)d_in[8];

    char* ws = (char*)d_ws;
    u16*   Xb16 = (u16*)ws;                              // [0, 64 MiB)
    u16*   Wcat = (u16*)(ws + 67108864 + 2097152);       // 655,360 B
    u16*   Wob  = (u16*)(ws + 67108864 + 2097152 + 655360); // 524,288 B
    u16*   qkv  = (u16*)d_out;                           // 80 MiB scratch in d_out
    float* Y    = (float*)d_out;

    k_wcvt <<<dim3((NO_ * C_ + C_ * C_ + 255) / 256), 256, 0, stream>>>(Wq, Wk, Wv, Wo, Wcat, Wob);
    k_proj <<<dim3(HW_ / 128, NO_ / 128, B_), 256, 0, stream>>>(Wcat, x, bq, bk, bv, qkv);
    k_attn <<<dim3(4, 8, B_), 512, 0, stream>>>(qkv, Xb16);
    k_out  <<<dim3(C_ / 128, (B_ * HW_) / 128), 256, 0, stream>>>(Xb16, Wob, bo, Y);
}